// Round 3
// baseline (154.611 us; speedup 1.0000x reference)
//
#include <hip/hip_runtime.h>
#include <math.h>

namespace {
constexpr int kB = 8, kL = 512, kD = 64, kS = 8;
constexpr int TILE = 64, PAD = 68;  // 16B-aligned rows; (row,col4) bank spread
constexpr int T_ELEMS = kB * kS * kL * kD;   // 2,097,152 floats (8 MB exactly)
}

// ---------- Stage 1 (fast path): T[b,s,i,e] = sum_d lstm1[b,i,d] * W[s,d,e] ----------
__global__ __launch_bounds__(256) void grn_stage(
    const float* __restrict__ lstm1, const float* __restrict__ W,
    float* __restrict__ T)
{
    const int s  = blockIdx.x;
    const int it = blockIdx.y;
    const int b  = blockIdx.z;
    __shared__ float x1[TILE][PAD];
    __shared__ float ws[kD][PAD];
    const int tid = threadIdx.x;
    {
        const float* p1 = lstm1 + (b * kL + it * TILE) * kD;
        const float* pw = W + s * kD * kD;
        const int c4 = (tid & 15) * 4;
        for (int rr = tid >> 4; rr < TILE; rr += 16) {
            *(float4*)(&x1[rr][c4]) = *(const float4*)(p1 + rr * kD + c4);
            *(float4*)(&ws[rr][c4]) = *(const float4*)(pw + rr * kD + c4);
        }
    }
    __syncthreads();
    const int tx = tid & 15, ty = tid >> 4;
    float acc[4][4];
    #pragma unroll
    for (int i = 0; i < 4; i++)
        #pragma unroll
        for (int j = 0; j < 4; j++) acc[i][j] = 0.f;
    #pragma unroll 4
    for (int d4 = 0; d4 < 16; d4++) {
        float4 av[4];
        #pragma unroll
        for (int ii = 0; ii < 4; ii++)
            av[ii] = *(const float4*)(&x1[ty * 4 + ii][d4 * 4]);
        #pragma unroll
        for (int k = 0; k < 4; k++) {
            const float4 wv = *(const float4*)(&ws[d4 * 4 + k][tx * 4]);
            #pragma unroll
            for (int ii = 0; ii < 4; ii++) {
                const float a = ((const float*)&av[ii])[k];
                acc[ii][0] = fmaf(a, wv.x, acc[ii][0]);
                acc[ii][1] = fmaf(a, wv.y, acc[ii][1]);
                acc[ii][2] = fmaf(a, wv.z, acc[ii][2]);
                acc[ii][3] = fmaf(a, wv.w, acc[ii][3]);
            }
        }
    }
    float* tp = T + ((b * kS + s) * kL + it * TILE) * kD;
    #pragma unroll
    for (int ii = 0; ii < 4; ii++) {
        float4 o = {acc[ii][0], acc[ii][1], acc[ii][2], acc[ii][3]};
        *(float4*)(tp + (ty * 4 + ii) * kD + tx * 4) = o;
    }
}

// ---------- shared epilogue helper ----------
__device__ __forceinline__ void grn_epilogue(
    float acc[4][4], float oacc[4][4],
    const float scl[4][kS][TILE], int s, int ty, int tx,
    float us, float bgs)
{
    float v1i[4], g1i[4], v2j[4], g2j[4];
    #pragma unroll
    for (int ii = 0; ii < 4; ii++) {
        v1i[ii] = scl[0][s][ty * 4 + ii];
        g1i[ii] = scl[1][s][ty * 4 + ii];
    }
    #pragma unroll
    for (int jj = 0; jj < 4; jj++) {
        v2j[jj] = scl[2][s][tx * 4 + jj];
        g2j[jj] = scl[3][s][tx * 4 + jj];
    }
    #pragma unroll
    for (int ii = 0; ii < 4; ii++)
        #pragma unroll
        for (int jj = 0; jj < 4; jj++) {
            const float gv = g1i[ii] + g2j[jj] + bgs;
            const float gate = 1.f / (1.f + __expf(-gv));
            const float sv = 1.f / (1.f + __expf(-(v1i[ii] + v2j[jj])));
            const float res = fmaf(gate, acc[ii][jj] - sv, sv);
            oacc[ii][jj] = fmaf(us, res, oacc[ii][jj]);
        }
}

// per-thread scalar-dot computation into scl (after x1/x2 staged, before use)
__device__ __forceinline__ void grn_scalars(
    float scl[4][kS][TILE], const float x1[TILE][PAD], const float x2[TILE][PAD],
    const float* __restrict__ V, const float* __restrict__ Wg, int tid)
{
    const int kind = tid >> 6;          // 0:v1 1:g1 2:v2 3:g2
    const int row  = tid & 63;
    const float* base = (kind == 0) ? V : (kind == 1) ? Wg
                      : (kind == 2) ? (V + kD) : (Wg + kD);
    const float(*xs)[PAD] = (kind < 2) ? x1 : x2;
    #pragma unroll
    for (int s = 0; s < kS; s++) {
        const float* vec = base + s * 2 * kD;
        float a = 0.f;
        #pragma unroll 4
        for (int d4 = 0; d4 < 16; d4++) {
            const float4 vv = *(const float4*)(vec + d4 * 4);
            const float4 xv = *(const float4*)(&xs[row][d4 * 4]);
            a = fmaf(vv.x, xv.x, a); a = fmaf(vv.y, xv.y, a);
            a = fmaf(vv.z, xv.z, a); a = fmaf(vv.w, xv.w, a);
        }
        scl[kind][s][row] = a;
    }
}

// ---------- Stage 2 (fast path): reads precomputed T ----------
__global__ __launch_bounds__(256) void grn_main(
    const float* __restrict__ lstm1, const float* __restrict__ lstm2,
    const float* __restrict__ T, const float* __restrict__ V,
    const float* __restrict__ bS, const float* __restrict__ Wg,
    const float* __restrict__ bg, const float* __restrict__ u,
    float* __restrict__ out)
{
    const int jt = blockIdx.x, it = blockIdx.y, b = blockIdx.z;
    __shared__ float x1[TILE][PAD];
    __shared__ float x2[TILE][PAD];
    __shared__ float ts[TILE][PAD];
    __shared__ float scl[4][kS][TILE];
    const int tid = threadIdx.x;
    {
        const float* p1 = lstm1 + (b * kL + it * TILE) * kD;
        const float* p2 = lstm2 + (b * kL + jt * TILE) * kD;
        const int c4 = (tid & 15) * 4;
        for (int rr = tid >> 4; rr < TILE; rr += 16) {
            *(float4*)(&x1[rr][c4]) = *(const float4*)(p1 + rr * kD + c4);
            *(float4*)(&x2[rr][c4]) = *(const float4*)(p2 + rr * kD + c4);
        }
    }
    __syncthreads();
    grn_scalars(scl, x1, x2, V, Wg, tid);

    const int tx = tid & 15, ty = tid >> 4;
    float bias_c = 0.f;
    #pragma unroll
    for (int s = 0; s < kS; s++) bias_c = fmaf(u[s], bS[s], bias_c);
    float oacc[4][4];
    #pragma unroll
    for (int i = 0; i < 4; i++)
        #pragma unroll
        for (int j = 0; j < 4; j++) oacc[i][j] = bias_c;

    for (int s = 0; s < kS; s++) {
        __syncthreads();   // prior ts reads done (also covers scl writes on s==0)
        {
            const float* tp = T + ((b * kS + s) * kL + it * TILE) * kD;
            const int c4 = (tid & 15) * 4;
            for (int rr = tid >> 4; rr < TILE; rr += 16)
                *(float4*)(&ts[rr][c4]) = *(const float4*)(tp + rr * kD + c4);
        }
        __syncthreads();
        float acc[4][4];
        #pragma unroll
        for (int i = 0; i < 4; i++)
            #pragma unroll
            for (int j = 0; j < 4; j++) acc[i][j] = 0.f;
        #pragma unroll 4
        for (int e4 = 0; e4 < 16; e4++) {
            float4 av[4], bv[4];
            #pragma unroll
            for (int ii = 0; ii < 4; ii++)
                av[ii] = *(const float4*)(&ts[ty * 4 + ii][e4 * 4]);
            #pragma unroll
            for (int jj = 0; jj < 4; jj++)
                bv[jj] = *(const float4*)(&x2[tx * 4 + jj][e4 * 4]);
            #pragma unroll
            for (int k = 0; k < 4; k++)
                #pragma unroll
                for (int ii = 0; ii < 4; ii++) {
                    const float a = ((const float*)&av[ii])[k];
                    #pragma unroll
                    for (int jj = 0; jj < 4; jj++)
                        acc[ii][jj] = fmaf(a, ((const float*)&bv[jj])[k], acc[ii][jj]);
                }
        }
        grn_epilogue(acc, oacc, scl, s, ty, tx, u[s], bg[s]);
    }
    float* op = out + (b * kL + it * TILE) * kL + jt * TILE;
    #pragma unroll
    for (int ii = 0; ii < 4; ii++) {
        float4 o = {oacc[ii][0], oacc[ii][1], oacc[ii][2], oacc[ii][3]};
        *(float4*)(op + (ty * 4 + ii) * kL + tx * 4) = o;
    }
}

// ---------- Fallback: fully fused, zero workspace (recomputes x1@W_s per block) ----------
__global__ __launch_bounds__(256) void grn_fused(
    const float* __restrict__ lstm1, const float* __restrict__ lstm2,
    const float* __restrict__ W, const float* __restrict__ V,
    const float* __restrict__ bS, const float* __restrict__ Wg,
    const float* __restrict__ bg, const float* __restrict__ u,
    float* __restrict__ out)
{
    const int jt = blockIdx.x, it = blockIdx.y, b = blockIdx.z;
    __shared__ float x1[TILE][PAD];
    __shared__ float x2[TILE][PAD];
    __shared__ float w [kD][PAD];
    __shared__ float ts[TILE][PAD];
    __shared__ float scl[4][kS][TILE];
    const int tid = threadIdx.x;
    {
        const float* p1 = lstm1 + (b * kL + it * TILE) * kD;
        const float* p2 = lstm2 + (b * kL + jt * TILE) * kD;
        const int c4 = (tid & 15) * 4;
        for (int rr = tid >> 4; rr < TILE; rr += 16) {
            *(float4*)(&x1[rr][c4]) = *(const float4*)(p1 + rr * kD + c4);
            *(float4*)(&x2[rr][c4]) = *(const float4*)(p2 + rr * kD + c4);
        }
    }
    __syncthreads();
    grn_scalars(scl, x1, x2, V, Wg, tid);

    const int tx = tid & 15, ty = tid >> 4;
    float bias_c = 0.f;
    #pragma unroll
    for (int s = 0; s < kS; s++) bias_c = fmaf(u[s], bS[s], bias_c);
    float oacc[4][4];
    #pragma unroll
    for (int i = 0; i < 4; i++)
        #pragma unroll
        for (int j = 0; j < 4; j++) oacc[i][j] = bias_c;

    for (int s = 0; s < kS; s++) {
        __syncthreads();   // prior iter's w/ts reads done (covers scl on s==0)
        {
            const float* pw = W + s * kD * kD;
            const int c4 = (tid & 15) * 4;
            for (int rr = tid >> 4; rr < TILE; rr += 16)
                *(float4*)(&w[rr][c4]) = *(const float4*)(pw + rr * kD + c4);
        }
        __syncthreads();   // w ready
        // ts = x1 @ w  (each thread a 4x4 micro-tile)
        float tacc[4][4];
        #pragma unroll
        for (int i = 0; i < 4; i++)
            #pragma unroll
            for (int j = 0; j < 4; j++) tacc[i][j] = 0.f;
        #pragma unroll 4
        for (int d4 = 0; d4 < 16; d4++) {
            float4 av[4];
            #pragma unroll
            for (int ii = 0; ii < 4; ii++)
                av[ii] = *(const float4*)(&x1[ty * 4 + ii][d4 * 4]);
            #pragma unroll
            for (int k = 0; k < 4; k++) {
                const float4 wv = *(const float4*)(&w[d4 * 4 + k][tx * 4]);
                #pragma unroll
                for (int ii = 0; ii < 4; ii++) {
                    const float a = ((const float*)&av[ii])[k];
                    tacc[ii][0] = fmaf(a, wv.x, tacc[ii][0]);
                    tacc[ii][1] = fmaf(a, wv.y, tacc[ii][1]);
                    tacc[ii][2] = fmaf(a, wv.z, tacc[ii][2]);
                    tacc[ii][3] = fmaf(a, wv.w, tacc[ii][3]);
                }
            }
        }
        #pragma unroll
        for (int ii = 0; ii < 4; ii++) {
            float4 o = {tacc[ii][0], tacc[ii][1], tacc[ii][2], tacc[ii][3]};
            *(float4*)(&ts[ty * 4 + ii][tx * 4]) = o;
        }
        __syncthreads();   // ts ready
        float acc[4][4];
        #pragma unroll
        for (int i = 0; i < 4; i++)
            #pragma unroll
            for (int j = 0; j < 4; j++) acc[i][j] = 0.f;
        #pragma unroll 4
        for (int e4 = 0; e4 < 16; e4++) {
            float4 av[4], bv[4];
            #pragma unroll
            for (int ii = 0; ii < 4; ii++)
                av[ii] = *(const float4*)(&ts[ty * 4 + ii][e4 * 4]);
            #pragma unroll
            for (int jj = 0; jj < 4; jj++)
                bv[jj] = *(const float4*)(&x2[tx * 4 + jj][e4 * 4]);
            #pragma unroll
            for (int k = 0; k < 4; k++)
                #pragma unroll
                for (int ii = 0; ii < 4; ii++) {
                    const float a = ((const float*)&av[ii])[k];
                    #pragma unroll
                    for (int jj = 0; jj < 4; jj++)
                        acc[ii][jj] = fmaf(a, ((const float*)&bv[jj])[k], acc[ii][jj]);
                }
        }
        grn_epilogue(acc, oacc, scl, s, ty, tx, u[s], bg[s]);
    }
    float* op = out + (b * kL + it * TILE) * kL + jt * TILE;
    #pragma unroll
    for (int ii = 0; ii < 4; ii++) {
        float4 o = {oacc[ii][0], oacc[ii][1], oacc[ii][2], oacc[ii][3]};
        *(float4*)(op + (ty * 4 + ii) * kL + tx * 4) = o;
    }
}

extern "C" void kernel_launch(void* const* d_in, const int* in_sizes, int n_in,
                              void* d_out, int out_size, void* d_ws, size_t ws_size,
                              hipStream_t stream) {
    const float* lstm1 = (const float*)d_in[0];
    const float* lstm2 = (const float*)d_in[1];
    const float* W     = (const float*)d_in[2];
    const float* V     = (const float*)d_in[3];
    const float* bS    = (const float*)d_in[4];
    const float* Wg    = (const float*)d_in[5];
    const float* bg    = (const float*)d_in[6];
    const float* u     = (const float*)d_in[7];
    float* out = (float*)d_out;
    const size_t T_BYTES = (size_t)T_ELEMS * sizeof(float);
    if (ws_size >= T_BYTES) {
        float* T = (float*)d_ws;
        dim3 gA(kS, kL / TILE, kB);            // 512 blocks
        grn_stage<<<gA, 256, 0, stream>>>(lstm1, W, T);
        dim3 gB(kL / TILE, kL / TILE, kB);     // 512 blocks
        grn_main<<<gB, 256, 0, stream>>>(lstm1, lstm2, T, V, bS, Wg, bg, u, out);
    } else {
        dim3 gB(kL / TILE, kL / TILE, kB);     // 512 blocks, no workspace
        grn_fused<<<gB, 256, 0, stream>>>(lstm1, lstm2, W, V, bS, Wg, bg, u, out);
    }
}

// Round 5
// 114.681 us; speedup vs baseline: 1.3482x; 1.3482x over previous
//
#include <hip/hip_runtime.h>
#include <math.h>

typedef float f32x4 __attribute__((ext_vector_type(4)));
typedef short bf16x8 __attribute__((ext_vector_type(8)));  // 8 bf16 in 4 VGPR (guide §3)

namespace {
constexpr int kB = 8, kL = 512, kD = 64, kS = 8;
constexpr int LP = 72;  // bf16 LDS row pad: 144B rows -> balanced banks for b128 frags
// workspace byte offsets
constexpr size_t SCL_OFF = 0;                                  // f32[4][8][8][512] = 512KB
constexpr size_t WT_OFF  = (size_t)4 * 8 * 8 * 512 * 4;        // 524288
constexpr size_t T_OFF   = WT_OFF + (size_t)8 * 64 * 64 * 2;   // +64KB = 589824; T bf16 = 4MB
}

__device__ __forceinline__ unsigned short f2bf(float f) {      // RNE float->bf16 bits
    unsigned u = __float_as_uint(f);
    u += 0x7FFFu + ((u >> 16) & 1u);
    return (unsigned short)(u >> 16);
}
__device__ __forceinline__ unsigned pk2(float lo, float hi) {
    return (unsigned)f2bf(lo) | ((unsigned)f2bf(hi) << 16);
}

// ---------------- P: W^T -> bf16 (blocks 0..7) + scalar dots scl (blocks 8..71) ----------
__global__ __launch_bounds__(256) void grn_prep(
    const float* __restrict__ lstm1, const float* __restrict__ lstm2,
    const float* __restrict__ W, const float* __restrict__ V,
    const float* __restrict__ Wg, unsigned char* __restrict__ ws)
{
    float* scl = (float*)(ws + SCL_OFF);
    unsigned short* wt = (unsigned short*)(ws + WT_OFF);
    const int tid = threadIdx.x;
    if (blockIdx.x < 8) {
        const int s = blockIdx.x;
        __shared__ float wsm[64][68];
        const float* pw = W + s * 4096;
        const int row = tid >> 2, c0 = (tid & 3) * 16;
        #pragma unroll
        for (int q = 0; q < 4; q++)
            *(float4*)&wsm[row][c0 + q * 4] = *(const float4*)(pw + row * 64 + c0 + q * 4);
        __syncthreads();
        // wt[s][e][d] = W[s][d][e]
        const int e = tid >> 2, d0 = (tid & 3) * 16;
        unsigned wd[8];
        #pragma unroll
        for (int q = 0; q < 8; q++)
            wd[q] = pk2(wsm[d0 + 2 * q][e], wsm[d0 + 2 * q + 1][e]);
        unsigned short* dst = wt + s * 4096 + e * 64 + d0;
        uint4 a = {wd[0], wd[1], wd[2], wd[3]};
        uint4 c = {wd[4], wd[5], wd[6], wd[7]};
        *(uint4*)(dst) = a;
        *(uint4*)(dst + 8) = c;
    } else {
        const int rb = blockIdx.x - 8;
        const int b = rb >> 3, r0 = (rb & 7) * 64;
        const int kind = tid & 3, row = r0 + (tid >> 2);
        const float* x = (kind < 2 ? lstm1 : lstm2) + ((size_t)b * kL + row) * kD;
        float xr[64];
        #pragma unroll
        for (int q = 0; q < 16; q++)
            *(float4*)&xr[q * 4] = *(const float4*)(x + q * 4);
        const float* vb = (kind & 1 ? Wg : V) + ((kind >> 1) ? kD : 0);
        #pragma unroll
        for (int s = 0; s < kS; s++) {
            const float* vec = vb + s * 2 * kD;
            float a = 0.f;
            #pragma unroll
            for (int q = 0; q < 16; q++) {
                const float4 vv = *(const float4*)(vec + q * 4);
                a = fmaf(vv.x, xr[q * 4 + 0], a);
                a = fmaf(vv.y, xr[q * 4 + 1], a);
                a = fmaf(vv.z, xr[q * 4 + 2], a);
                a = fmaf(vv.w, xr[q * 4 + 3], a);
            }
            scl[(((size_t)kind * 8 + b) * 8 + s) * 512 + row] = a;
        }
    }
}

// ---------------- P2: T[b,s,i,e] = x1 @ W_s  (bf16 MFMA, T stored bf16) ----------------
__global__ __launch_bounds__(256) void grn_t(
    const float* __restrict__ lstm1, unsigned char* __restrict__ ws)
{
    const unsigned short* wt = (const unsigned short*)(ws + WT_OFF);
    unsigned short* T = (unsigned short*)(ws + T_OFF);
    const int s = blockIdx.x, it = blockIdx.y, b = blockIdx.z;
    __shared__ __align__(16) unsigned short x1t[64][LP];
    __shared__ __align__(16) unsigned short wtt[64][LP];
    const int tid = threadIdx.x;
    {   // x1 tile f32 -> bf16 LDS
        const float* p = lstm1 + ((size_t)b * kL + it * 64) * kD;
        const int row = tid >> 2, c0 = (tid & 3) * 16;
        unsigned wd[8];
        #pragma unroll
        for (int q = 0; q < 4; q++) {
            const float4 v = *(const float4*)(p + row * 64 + c0 + q * 4);
            wd[q * 2 + 0] = pk2(v.x, v.y);
            wd[q * 2 + 1] = pk2(v.z, v.w);
        }
        uint4 a = {wd[0], wd[1], wd[2], wd[3]};
        uint4 c = {wd[4], wd[5], wd[6], wd[7]};
        *(uint4*)&x1t[row][c0] = a;
        *(uint4*)&x1t[row][c0 + 8] = c;
    }
    {   // wt_s bf16 -> LDS
        const unsigned short* g = wt + s * 4096;
        #pragma unroll
        for (int k = 0; k < 2; k++) {
            const int q = tid + k * 256;
            *(uint4*)&wtt[q >> 3][(q & 7) * 8] = *(const uint4*)(g + q * 8);
        }
    }
    __syncthreads();
    const int lane = tid & 63, w = tid >> 6;
    const int wm = w >> 1, wn = w & 1;
    const int fr = lane & 15, fh = lane >> 4;
    bf16x8 A[2][2], Bf[2][2];
    #pragma unroll
    for (int mb = 0; mb < 2; mb++)
        #pragma unroll
        for (int kb = 0; kb < 2; kb++)
            A[mb][kb] = *(const bf16x8*)&x1t[wm * 32 + mb * 16 + fr][fh * 8 + kb * 32];
    #pragma unroll
    for (int nb = 0; nb < 2; nb++)
        #pragma unroll
        for (int kb = 0; kb < 2; kb++)
            Bf[nb][kb] = *(const bf16x8*)&wtt[wn * 32 + nb * 16 + fr][fh * 8 + kb * 32];
    unsigned short* tb = T + (((size_t)(b * 8 + s)) * 512 + it * 64) * 64;
    #pragma unroll
    for (int mb = 0; mb < 2; mb++)
        #pragma unroll
        for (int nb = 0; nb < 2; nb++) {
            f32x4 z = {0.f, 0.f, 0.f, 0.f};
            f32x4 acc = __builtin_amdgcn_mfma_f32_16x16x32_bf16(A[mb][0], Bf[nb][0], z, 0, 0, 0);
            acc = __builtin_amdgcn_mfma_f32_16x16x32_bf16(A[mb][1], Bf[nb][1], acc, 0, 0, 0);
            const int e = wn * 32 + nb * 16 + fr;
            #pragma unroll
            for (int r = 0; r < 4; r++) {
                const int i = wm * 32 + mb * 16 + fh * 4 + r;  // D: row=(lane>>4)*4+reg
                tb[i * 64 + e] = f2bf(acc[r]);
            }
        }
}

// ---------------- Main: rw = T_s @ x2^T (MFMA) + fused gate/sigmoid/u epilogue ----------
__global__ __launch_bounds__(256) void grn_mainm(
    const float* __restrict__ lstm2, const float* __restrict__ bS,
    const float* __restrict__ bg, const float* __restrict__ u,
    const unsigned char* __restrict__ ws, float* __restrict__ out)
{
    const float* sclw = (const float*)(ws + SCL_OFF);
    const unsigned short* T = (const unsigned short*)(ws + T_OFF);
    const int jt = blockIdx.x, it = blockIdx.y, b = blockIdx.z;
    __shared__ __align__(16) unsigned short x2t[64][LP];
    __shared__ __align__(16) unsigned short tst[64][LP];
    __shared__ float scl[4][kS][64];
    const int tid = threadIdx.x;
    {   // x2 tile f32 -> bf16 LDS
        const float* p = lstm2 + ((size_t)b * kL + jt * 64) * kD;
        const int row = tid >> 2, c0 = (tid & 3) * 16;
        unsigned wd[8];
        #pragma unroll
        for (int q = 0; q < 4; q++) {
            const float4 v = *(const float4*)(p + row * 64 + c0 + q * 4);
            wd[q * 2 + 0] = pk2(v.x, v.y);
            wd[q * 2 + 1] = pk2(v.z, v.w);
        }
        uint4 a = {wd[0], wd[1], wd[2], wd[3]};
        uint4 c = {wd[4], wd[5], wd[6], wd[7]};
        *(uint4*)&x2t[row][c0] = a;
        *(uint4*)&x2t[row][c0 + 8] = c;
    }
    {   // scl slices: kinds 0,1 use it-rows; 2,3 use jt-rows
        const int p0 = tid * 8, kind = p0 >> 9, rem = p0 & 511, s = rem >> 6, cc = rem & 63;
        const int base = (kind < 2 ? it : jt) * 64;
        const float* g = sclw + (((size_t)kind * 8 + b) * 8 + s) * 512 + base + cc;
        *(float4*)&scl[kind][s][cc] = *(const float4*)g;
        *(float4*)&scl[kind][s][cc + 4] = *(const float4*)(g + 4);
    }
    __syncthreads();
    const int lane = tid & 63, w = tid >> 6;
    const int wm = w >> 1, wn = w & 1;
    const int fr = lane & 15, fh = lane >> 4;
    bf16x8 Bf[2][2];
    #pragma unroll
    for (int nb = 0; nb < 2; nb++)
        #pragma unroll
        for (int kb = 0; kb < 2; kb++)
            Bf[nb][kb] = *(const bf16x8*)&x2t[wn * 32 + nb * 16 + fr][fh * 8 + kb * 32];
    float bias_c = 0.f;
    #pragma unroll
    for (int s = 0; s < kS; s++) bias_c = fmaf(u[s], bS[s], bias_c);
    float oacc[2][2][4];
    #pragma unroll
    for (int mb = 0; mb < 2; mb++)
        #pragma unroll
        for (int nb = 0; nb < 2; nb++)
            #pragma unroll
            for (int r = 0; r < 4; r++) oacc[mb][nb][r] = bias_c;

    for (int s = 0; s < kS; s++) {
        __syncthreads();   // previous tst reads complete
        {
            const unsigned short* tb = T + (((size_t)(b * 8 + s)) * 512 + it * 64) * 64;
            #pragma unroll
            for (int k = 0; k < 2; k++) {
                const int q = tid + k * 256;
                *(uint4*)&tst[q >> 3][(q & 7) * 8] = *(const uint4*)(tb + q * 8);
            }
        }
        __syncthreads();
        bf16x8 A[2][2];
        #pragma unroll
        for (int mb = 0; mb < 2; mb++)
            #pragma unroll
            for (int kb = 0; kb < 2; kb++)
                A[mb][kb] = *(const bf16x8*)&tst[wm * 32 + mb * 16 + fr][fh * 8 + kb * 32];
        const float us = u[s], bgs = bg[s];
        #pragma unroll
        for (int mb = 0; mb < 2; mb++)
            #pragma unroll
            for (int nb = 0; nb < 2; nb++) {
                f32x4 z = {0.f, 0.f, 0.f, 0.f};
                f32x4 acc = __builtin_amdgcn_mfma_f32_16x16x32_bf16(A[mb][0], Bf[nb][0], z, 0, 0, 0);
                acc = __builtin_amdgcn_mfma_f32_16x16x32_bf16(A[mb][1], Bf[nb][1], acc, 0, 0, 0);
                const int jj = wn * 32 + nb * 16 + fr;
                const float v2 = scl[2][s][jj], g2 = scl[3][s][jj];
                #pragma unroll
                for (int r = 0; r < 4; r++) {
                    const int ii = wm * 32 + mb * 16 + fh * 4 + r;
                    const float v1 = scl[0][s][ii], g1 = scl[1][s][ii];
                    const float gate = 1.f / (1.f + __expf(-(g1 + g2 + bgs)));
                    const float sv = 1.f / (1.f + __expf(-(v1 + v2)));
                    const float res = fmaf(gate, acc[r] - sv, sv);  // gate*rw+(1-gate)*sv
                    oacc[mb][nb][r] = fmaf(us, res, oacc[mb][nb][r]);
                }
            }
    }
    float* op = out + ((size_t)b * kL + it * 64) * kL + jt * 64;
    #pragma unroll
    for (int mb = 0; mb < 2; mb++)
        #pragma unroll
        for (int nb = 0; nb < 2; nb++)
            #pragma unroll
            for (int r = 0; r < 4; r++)
                op[(wm * 32 + mb * 16 + fh * 4 + r) * kL + wn * 32 + nb * 16 + fr]
                    = oacc[mb][nb][r];
}

extern "C" void kernel_launch(void* const* d_in, const int* in_sizes, int n_in,
                              void* d_out, int out_size, void* d_ws, size_t ws_size,
                              hipStream_t stream) {
    const float* lstm1 = (const float*)d_in[0];
    const float* lstm2 = (const float*)d_in[1];
    const float* W     = (const float*)d_in[2];
    const float* V     = (const float*)d_in[3];
    const float* bS    = (const float*)d_in[4];
    const float* Wg    = (const float*)d_in[5];
    const float* bg    = (const float*)d_in[6];
    const float* u     = (const float*)d_in[7];
    unsigned char* ws = (unsigned char*)d_ws;   // needs 4.6MB; ws_size >= 8MB (verified r3)
    grn_prep<<<72, 256, 0, stream>>>(lstm1, lstm2, W, V, Wg, ws);
    grn_t<<<dim3(kS, kL / 64, kB), 256, 0, stream>>>(lstm1, ws);
    grn_mainm<<<dim3(kL / 64, kL / 64, kB), 256, 0, stream>>>(lstm2, bS, bg, u, ws, (float*)d_out);
}

// Round 6
// 110.750 us; speedup vs baseline: 1.3960x; 1.0355x over previous
//
#include <hip/hip_runtime.h>
#include <math.h>

typedef float f32x4 __attribute__((ext_vector_type(4)));
typedef short bf16x8 __attribute__((ext_vector_type(8)));  // 8 bf16 in 4 VGPR (guide §3)

namespace {
constexpr int kB = 8, kL = 512, kD = 64, kS = 8;
constexpr int LP = 72;  // bf16 LDS row pad: 144B rows
// workspace byte offsets (total use ~576 KB)
constexpr size_t SCL_OFF = 0;                                  // f32[4][8][8][512] = 512KB
constexpr size_t WT_OFF  = (size_t)4 * 8 * 8 * 512 * 4;        // 524288; wt bf16 64KB
}

__device__ __forceinline__ unsigned short f2bf(float f) {      // RNE float->bf16 bits
    unsigned u = __float_as_uint(f);
    u += 0x7FFFu + ((u >> 16) & 1u);
    return (unsigned short)(u >> 16);
}
__device__ __forceinline__ unsigned pk2(float lo, float hi) {
    return (unsigned)f2bf(lo) | ((unsigned)f2bf(hi) << 16);
}

// ---------------- P: W^T -> bf16 (blocks 0..7) + scalar dots scl (blocks 8..71) ----------
__global__ __launch_bounds__(256) void grn_prep(
    const float* __restrict__ lstm1, const float* __restrict__ lstm2,
    const float* __restrict__ W, const float* __restrict__ V,
    const float* __restrict__ Wg, unsigned char* __restrict__ ws)
{
    float* scl = (float*)(ws + SCL_OFF);
    unsigned short* wt = (unsigned short*)(ws + WT_OFF);
    const int tid = threadIdx.x;
    if (blockIdx.x < 8) {
        const int s = blockIdx.x;
        __shared__ float wsm[64][68];
        const float* pw = W + s * 4096;
        const int row = tid >> 2, c0 = (tid & 3) * 16;
        #pragma unroll
        for (int q = 0; q < 4; q++)
            *(float4*)&wsm[row][c0 + q * 4] = *(const float4*)(pw + row * 64 + c0 + q * 4);
        __syncthreads();
        // wt[s][e][d] = W[s][d][e]
        const int e = tid >> 2, d0 = (tid & 3) * 16;
        unsigned wd[8];
        #pragma unroll
        for (int q = 0; q < 8; q++)
            wd[q] = pk2(wsm[d0 + 2 * q][e], wsm[d0 + 2 * q + 1][e]);
        unsigned short* dst = wt + s * 4096 + e * 64 + d0;
        uint4 a = {wd[0], wd[1], wd[2], wd[3]};
        uint4 c = {wd[4], wd[5], wd[6], wd[7]};
        *(uint4*)(dst) = a;
        *(uint4*)(dst + 8) = c;
    } else {
        const int rb = blockIdx.x - 8;
        const int b = rb >> 3, r0 = (rb & 7) * 64;
        const int kind = tid & 3, row = r0 + (tid >> 2);
        const float* x = (kind < 2 ? lstm1 : lstm2) + ((size_t)b * kL + row) * kD;
        float xr[64];
        #pragma unroll
        for (int q = 0; q < 16; q++)
            *(float4*)&xr[q * 4] = *(const float4*)(x + q * 4);
        const float* vb = (kind & 1 ? Wg : V) + ((kind >> 1) ? kD : 0);
        #pragma unroll
        for (int s = 0; s < kS; s++) {
            const float* vec = vb + s * 2 * kD;
            float a = 0.f;
            #pragma unroll
            for (int q = 0; q < 16; q++) {
                const float4 vv = *(const float4*)(vec + q * 4);
                a = fmaf(vv.x, xr[q * 4 + 0], a);
                a = fmaf(vv.y, xr[q * 4 + 1], a);
                a = fmaf(vv.z, xr[q * 4 + 2], a);
                a = fmaf(vv.w, xr[q * 4 + 3], a);
            }
            scl[(((size_t)kind * 8 + b) * 8 + s) * 512 + row] = a;
        }
    }
}

// ---------------- Fused main: per s: T_s = x1@W_s^T (MFMA) -> LDS -> rw = T_s@x2^T ------
// Double-buffered wbuf/ts => ONE barrier per s-iteration; W_{s+1} prefetched to regs.
__global__ __launch_bounds__(256) void grn_fusedm(
    const float* __restrict__ lstm1, const float* __restrict__ lstm2,
    const float* __restrict__ bS, const float* __restrict__ bg,
    const float* __restrict__ u, const unsigned char* __restrict__ ws,
    float* __restrict__ out)
{
    const float* sclw = (const float*)(ws + SCL_OFF);
    const unsigned short* wt = (const unsigned short*)(ws + WT_OFF);
    const int jt = blockIdx.x, it = blockIdx.y, b = blockIdx.z;
    __shared__ __align__(16) unsigned short x1t[64][LP];
    __shared__ __align__(16) unsigned short x2t[64][LP];
    __shared__ __align__(16) unsigned short wbuf[2][64][LP];
    __shared__ __align__(16) unsigned short ts[2][64][LP];
    __shared__ float scl[4][kS][64];
    const int tid = threadIdx.x;
    {   // x1/x2 tiles f32 -> bf16 LDS
        const float* p1 = lstm1 + ((size_t)b * kL + it * 64) * kD;
        const float* p2 = lstm2 + ((size_t)b * kL + jt * 64) * kD;
        const int row = tid >> 2, c0 = (tid & 3) * 16;
        unsigned w1[8], w2[8];
        #pragma unroll
        for (int q = 0; q < 4; q++) {
            const float4 a = *(const float4*)(p1 + row * 64 + c0 + q * 4);
            const float4 c = *(const float4*)(p2 + row * 64 + c0 + q * 4);
            w1[q * 2] = pk2(a.x, a.y); w1[q * 2 + 1] = pk2(a.z, a.w);
            w2[q * 2] = pk2(c.x, c.y); w2[q * 2 + 1] = pk2(c.z, c.w);
        }
        uint4 a0 = {w1[0], w1[1], w1[2], w1[3]}, a1 = {w1[4], w1[5], w1[6], w1[7]};
        uint4 c0v = {w2[0], w2[1], w2[2], w2[3]}, c1 = {w2[4], w2[5], w2[6], w2[7]};
        *(uint4*)&x1t[row][c0] = a0; *(uint4*)&x1t[row][c0 + 8] = a1;
        *(uint4*)&x2t[row][c0] = c0v; *(uint4*)&x2t[row][c0 + 8] = c1;
    }
    {   // wbuf[0] = wt_0
        #pragma unroll
        for (int k = 0; k < 2; k++) {
            const int q = tid + k * 256;
            *(uint4*)&wbuf[0][q >> 3][(q & 7) * 8] = *(const uint4*)(wt + q * 8);
        }
    }
    {   // scl slices: kinds 0,1 use it-rows; 2,3 use jt-rows
        const int p0 = tid * 8, kind = p0 >> 9, rem = p0 & 511, s = rem >> 6, cc = rem & 63;
        const int base = (kind < 2 ? it : jt) * 64;
        const float* g = sclw + (((size_t)kind * 8 + b) * 8 + s) * 512 + base + cc;
        *(float4*)&scl[kind][s][cc] = *(const float4*)g;
        *(float4*)&scl[kind][s][cc + 4] = *(const float4*)(g + 4);
    }
    __syncthreads();
    const int lane = tid & 63, w = tid >> 6;
    const int wm = w >> 1, wn = w & 1;
    const int fr = lane & 15, fh = lane >> 4;
    // persistent fragments
    bf16x8 A1[2][2], Bf[2][2];
    #pragma unroll
    for (int mb = 0; mb < 2; mb++)
        #pragma unroll
        for (int kb = 0; kb < 2; kb++)
            A1[mb][kb] = *(const bf16x8*)&x1t[wm * 32 + mb * 16 + fr][fh * 8 + kb * 32];
    #pragma unroll
    for (int nb = 0; nb < 2; nb++)
        #pragma unroll
        for (int kb = 0; kb < 2; kb++)
            Bf[nb][kb] = *(const bf16x8*)&x2t[wn * 32 + nb * 16 + fr][fh * 8 + kb * 32];
    // prefetch wt_1 into regs
    uint4 wreg0 = *(const uint4*)(wt + 4096 + tid * 8);
    uint4 wreg1 = *(const uint4*)(wt + 4096 + (tid + 256) * 8);

    float bias_c = 0.f;
    #pragma unroll
    for (int s = 0; s < kS; s++) bias_c = fmaf(u[s], bS[s], bias_c);
    float oacc[2][2][4];
    #pragma unroll
    for (int mb = 0; mb < 2; mb++)
        #pragma unroll
        for (int nb = 0; nb < 2; nb++)
            #pragma unroll
            for (int r = 0; r < 4; r++) oacc[mb][nb][r] = bias_c;

    #pragma unroll 1
    for (int s = 0; s < kS; s++) {
        const int p = s & 1;
        // T_s = x1 @ W_s^T : B-frag rows of wbuf are e, cols d (wt[e][d]=W[d][e])
        bf16x8 WB[2][2];
        #pragma unroll
        for (int nb = 0; nb < 2; nb++)
            #pragma unroll
            for (int kb = 0; kb < 2; kb++)
                WB[nb][kb] = *(const bf16x8*)&wbuf[p][wn * 32 + nb * 16 + fr][fh * 8 + kb * 32];
        #pragma unroll
        for (int mb = 0; mb < 2; mb++)
            #pragma unroll
            for (int nb = 0; nb < 2; nb++) {
                f32x4 z = {0.f, 0.f, 0.f, 0.f};
                f32x4 tacc = __builtin_amdgcn_mfma_f32_16x16x32_bf16(A1[mb][0], WB[nb][0], z, 0, 0, 0);
                tacc = __builtin_amdgcn_mfma_f32_16x16x32_bf16(A1[mb][1], WB[nb][1], tacc, 0, 0, 0);
                // D layout: col=fr (e), row=fh*4+r (i)  -> ts[p][i][e] bf16
                #pragma unroll
                for (int r = 0; r < 4; r++)
                    ts[p][wm * 32 + mb * 16 + fh * 4 + r][wn * 32 + nb * 16 + fr] = f2bf(tacc[r]);
            }
        // stash prefetched W_{s+1} into wbuf[1-p] (before barrier; read next iter)
        *(uint4*)&wbuf[1 - p][tid >> 3][(tid & 7) * 8] = wreg0;
        {
            const int q = tid + 256;
            *(uint4*)&wbuf[1 - p][q >> 3][(q & 7) * 8] = wreg1;
        }
        __syncthreads();
        // rw = T_s @ x2^T
        bf16x8 At[2][2];
        #pragma unroll
        for (int mb = 0; mb < 2; mb++)
            #pragma unroll
            for (int kb = 0; kb < 2; kb++)
                At[mb][kb] = *(const bf16x8*)&ts[p][wm * 32 + mb * 16 + fr][fh * 8 + kb * 32];
        const float us = u[s], bgs = bg[s];
        #pragma unroll
        for (int mb = 0; mb < 2; mb++)
            #pragma unroll
            for (int nb = 0; nb < 2; nb++) {
                f32x4 z = {0.f, 0.f, 0.f, 0.f};
                f32x4 acc = __builtin_amdgcn_mfma_f32_16x16x32_bf16(At[mb][0], Bf[nb][0], z, 0, 0, 0);
                acc = __builtin_amdgcn_mfma_f32_16x16x32_bf16(At[mb][1], Bf[nb][1], acc, 0, 0, 0);
                const int jj = wn * 32 + nb * 16 + fr;
                const float v2 = scl[2][s][jj], g2 = scl[3][s][jj];
                #pragma unroll
                for (int r = 0; r < 4; r++) {
                    const int ii = wm * 32 + mb * 16 + fh * 4 + r;
                    const float v1 = scl[0][s][ii], g1 = scl[1][s][ii];
                    const float gate = 1.f / (1.f + __expf(-(g1 + g2 + bgs)));
                    const float sv = 1.f / (1.f + __expf(-(v1 + v2)));
                    const float res = fmaf(gate, acc[r] - sv, sv);  // gate*rw+(1-gate)*sv
                    oacc[mb][nb][r] = fmaf(us, res, oacc[mb][nb][r]);
                }
            }
        // issue prefetch of W_{s+2} (wraps harmlessly at the tail)
        const int sn = (s + 2) & 7;
        wreg0 = *(const uint4*)(wt + sn * 4096 + tid * 8);
        wreg1 = *(const uint4*)(wt + sn * 4096 + (tid + 256) * 8);
    }
    float* op = out + ((size_t)b * kL + it * 64) * kL + jt * 64;
    #pragma unroll
    for (int mb = 0; mb < 2; mb++)
        #pragma unroll
        for (int nb = 0; nb < 2; nb++)
            #pragma unroll
            for (int r = 0; r < 4; r++)
                op[(wm * 32 + mb * 16 + fh * 4 + r) * kL + wn * 32 + nb * 16 + fr]
                    = oacc[mb][nb][r];
}

extern "C" void kernel_launch(void* const* d_in, const int* in_sizes, int n_in,
                              void* d_out, int out_size, void* d_ws, size_t ws_size,
                              hipStream_t stream) {
    const float* lstm1 = (const float*)d_in[0];
    const float* lstm2 = (const float*)d_in[1];
    const float* W     = (const float*)d_in[2];
    const float* V     = (const float*)d_in[3];
    const float* bS    = (const float*)d_in[4];
    const float* Wg    = (const float*)d_in[5];
    const float* bg    = (const float*)d_in[6];
    const float* u     = (const float*)d_in[7];
    unsigned char* ws = (unsigned char*)d_ws;   // uses ~576 KB; ws_size >= 8MB verified
    grn_prep<<<72, 256, 0, stream>>>(lstm1, lstm2, W, V, Wg, ws);
    grn_fusedm<<<dim3(kL / 64, kL / 64, kB), 256, 0, stream>>>(
        lstm1, lstm2, bS, bg, u, ws, (float*)d_out);
}